// Round 2
// baseline (164.018 us; speedup 1.0000x reference)
//
#include <hip/hip_runtime.h>
#include <math.h>

#define BATCH 128
#define IH    128
#define IW    512
#define CH    3
#define OH    64
#define OW    256
#define KCP   20
#define KP3   23   // K + 3
#define RPB   2                   // output rows per block
#define YTILES (OH / RPB)         // 32

struct InvMat { float v[KP3 * KP3]; };

// ---------------------------------------------------------------------------
// Fused kernel: per-block TPS coefficient solve (tiny) + grid-gen + bilinear
// sampling. One block per RPB output rows of one image; thread x = out column.
// Block-id swizzle clusters all rows of an image on one XCD for L2 reuse.
// v2: dx^2 precomputed once per thread (shared across both cp rows AND both
// output rows), 0.5*log factor folded into the solved coefficients, 2 rows
// per block to amortize the T-solve and double in-flight loads per thread.
// ---------------------------------------------------------------------------
__global__ __launch_bounds__(256, 4) void tps_fused_kernel(InvMat inv,
                                                           const float* __restrict__ ctrl,
                                                           const float* __restrict__ X,
                                                           float* __restrict__ out) {
    int bid  = blockIdx.x;                // = ((b>>3)*YTILES + ytile)*8 + (b&7)
    int xcd  = bid & 7;
    int slot = bid >> 3;
    int ytile = slot & (YTILES - 1);
    int b = ((slot >> 5) << 3) | xcd;

    __shared__ float sc[KCP * 2];
    __shared__ float sT[KP3 * 2];
    int x = threadIdx.x;

    if (x < KCP * 2) sc[x] = ctrl[b * KCP * 2 + x];
    __syncthreads();
    if (x < KP3 * 2) {                    // T = INV_DELTA @ [ctrl; 0]
        int i = x >> 1, c = x & 1;
        float acc = 0.0f;
        #pragma unroll
        for (int j = 0; j < KCP; ++j)
            acc += inv.v[i * KP3 + j] * sc[j * 2 + c];
        // fold the 0.5 of r = d^2 * 0.5*log(d^2) into the RBF coefficients
        sT[x] = (i >= 3) ? 0.5f * acc : acc;
    }
    __syncthreads();

    float gx = ((float)x + 0.5f) * (1.0f / OW);

    // dx^2 to the 10 distinct control-point x positions — invariant across
    // the top/bottom cp rows and across all output rows this thread handles.
    float dx2[10];
    #pragma unroll
    for (int j = 0; j < 10; ++j) {
        float dx = gx - (0.05f + 0.1f * (float)j);
        dx2[j] = dx * dx;
    }

    #pragma unroll
    for (int r = 0; r < RPB; ++r) {
        int y = ytile * RPB + r;
        float gy = ((float)y + 0.5f) * (1.0f / OH);

        float px = sT[0] + gx * sT[2] + gy * sT[4];
        float py = sT[1] + gx * sT[3] + gy * sT[5];

        float dy0 = gy - 0.05f; float dyy0 = dy0 * dy0;
        float dy1 = gy - 0.95f; float dyy1 = dy1 * dy1;

        #pragma unroll
        for (int i = 0; i < KCP; ++i) {
            float d2 = dx2[i % 10] + ((i < 10) ? dyy0 : dyy1);
            float m = d2 * __logf(d2);        // = 2*d^2*log(d); 0.5 in sT
            px += m * sT[(3 + i) * 2 + 0];
            py += m * sT[(3 + i) * 2 + 1];
        }

        float Gx = fminf(fmaxf((float)IW * px, 0.0f), (float)(IW - 2));
        float Gy = fminf(fmaxf((float)IH * py, 0.0f), (float)(IH - 2));
        float fx0 = floorf(Gx), fy0 = floorf(Gy);
        int x0 = (int)fx0, y0 = (int)fy0;
        float fx = Gx - fx0, fy = Gy - fy0;

        const float* p00 = X + (((size_t)b * IH + y0) * IW + x0) * CH;  // (y0,x0),(y0,x1)
        const float* p01 = p00 + (size_t)IW * CH;                        // (y1,x0),(y1,x1)

        // 24 contiguous bytes per row segment (pixels x0,x1 x 3ch), align 4.
        // memcpy → wide unaligned loads. Exactly in-bounds (x0<=510,y0<=126).
        float r0[6], r1[6];
        __builtin_memcpy(r0, p00, 24);
        __builtin_memcpy(r1, p01, 24);

        float w00 = (1.0f - fx) * (1.0f - fy);
        float w10 = fx * (1.0f - fy);
        float w01 = (1.0f - fx) * fy;
        float w11 = fx * fy;

        float o0 = w00 * r0[0] + w10 * r0[3] + w01 * r1[0] + w11 * r1[3];
        float o1 = w00 * r0[1] + w10 * r0[4] + w01 * r1[1] + w11 * r1[4];
        float o2 = w00 * r0[2] + w10 * r0[5] + w01 * r1[2] + w11 * r1[5];

        // out is write-once — nontemporal keeps it from evicting X in L2.
        float* o = out + (((size_t)b * OH + y) * OW + x) * CH;
        __builtin_nontemporal_store(o0, o + 0);
        __builtin_nontemporal_store(o1, o + 1);
        __builtin_nontemporal_store(o2, o + 2);
    }
}

// ---------------------------------------------------------------------------
// Host
// ---------------------------------------------------------------------------
extern "C" void kernel_launch(void* const* d_in, const int* in_sizes, int n_in,
                              void* d_out, int out_size, void* d_ws, size_t ws_size,
                              hipStream_t stream) {
    const float* X    = (const float*)d_in[0];
    const float* ctrl = (const float*)d_in[1];
    float* out = (float*)d_out;

    // ---- host-side: control points + inverse delta matrix (float64) ----
    double C[KCP][2];
    for (int j = 0; j < 10; ++j) {
        C[j][0]      = 0.05 + 0.1 * j;  C[j][1]      = 0.05;
        C[10 + j][0] = 0.05 + 0.1 * j;  C[10 + j][1] = 0.95;
    }

    double A[KP3][2 * KP3];
    for (int i = 0; i < KP3; ++i)
        for (int j = 0; j < 2 * KP3; ++j) A[i][j] = 0.0;

    for (int i = 0; i < KCP; ++i) {
        A[i][0] = 1.0; A[i][1] = C[i][0]; A[i][2] = C[i][1];
        for (int j = 0; j < KCP; ++j) {
            if (i == j) { A[i][3 + j] = 0.0; continue; }
            double dx = C[i][0] - C[j][0], dy = C[i][1] - C[j][1];
            double r2 = dx * dx + dy * dy;
            A[i][3 + j] = 0.5 * r2 * log(r2);   // r^2 * log(r)
        }
    }
    for (int j = 0; j < KCP; ++j) {
        A[KCP + 0][3 + j] = C[j][0];
        A[KCP + 1][3 + j] = C[j][1];
        A[KCP + 2][3 + j] = 1.0;
    }
    for (int i = 0; i < KP3; ++i) A[i][KP3 + i] = 1.0;   // augment identity

    // Gauss-Jordan with partial pivoting (float64, host)
    for (int k = 0; k < KP3; ++k) {
        int p = k; double best = fabs(A[k][k]);
        for (int i = k + 1; i < KP3; ++i)
            if (fabs(A[i][k]) > best) { best = fabs(A[i][k]); p = i; }
        if (p != k)
            for (int j = 0; j < 2 * KP3; ++j) { double t = A[k][j]; A[k][j] = A[p][j]; A[p][j] = t; }
        double pv = A[k][k];
        for (int j = 0; j < 2 * KP3; ++j) A[k][j] /= pv;
        for (int i = 0; i < KP3; ++i) {
            if (i == k) continue;
            double m = A[i][k];
            if (m == 0.0) continue;
            for (int j = 0; j < 2 * KP3; ++j) A[i][j] -= m * A[k][j];
        }
    }

    InvMat inv;
    for (int i = 0; i < KP3; ++i)
        for (int j = 0; j < KP3; ++j)
            inv.v[i * KP3 + j] = (float)A[i][KP3 + j];

    // ---- device: single fused kernel, RPB rows per block ----
    tps_fused_kernel<<<BATCH * YTILES, 256, 0, stream>>>(inv, ctrl, X, out);
}

// Round 3
// 161.596 us; speedup vs baseline: 1.0150x; 1.0150x over previous
//
#include <hip/hip_runtime.h>
#include <math.h>

#define BATCH 128
#define IH    128
#define IW    512
#define CH    3
#define OH    64
#define OW    256
#define KCP   20
#define KP3   23   // K + 3
#define RPB   2                   // output rows per block
#define YTILES (OH / RPB)         // 32

struct InvMat { float v[KP3 * KP3]; };

// ---------------------------------------------------------------------------
// Fused kernel: per-block TPS coefficient solve (tiny) + grid-gen + bilinear
// sampling. One block per RPB output rows of one image; thread x = out column.
// Block-id swizzle clusters all rows of an image on one XCD for L2 reuse.
// v3: both rows' RBF chains interleaved in ONE loop (ILP on the two log
// chains), all four 24B gather loads issued back-to-back BEFORE any blend
// math (MLP — lanes' y0 differ, so these are scattered-cacheline loads and
// latency-bound), and no min-waves bound (v2's (256,4) risked spilling the
// dx2[10] + 2-row live state).
// ---------------------------------------------------------------------------
__global__ __launch_bounds__(256) void tps_fused_kernel(InvMat inv,
                                                        const float* __restrict__ ctrl,
                                                        const float* __restrict__ X,
                                                        float* __restrict__ out) {
    int bid  = blockIdx.x;                // = ((b>>3)*YTILES + ytile)*8 + (b&7)
    int xcd  = bid & 7;
    int slot = bid >> 3;
    int ytile = slot & (YTILES - 1);
    int b = ((slot >> 5) << 3) | xcd;

    __shared__ float sc[KCP * 2];
    __shared__ float sT[KP3 * 2];
    int x = threadIdx.x;

    if (x < KCP * 2) sc[x] = ctrl[b * KCP * 2 + x];
    __syncthreads();
    if (x < KP3 * 2) {                    // T = INV_DELTA @ [ctrl; 0]
        int i = x >> 1, c = x & 1;
        float acc = 0.0f;
        #pragma unroll
        for (int j = 0; j < KCP; ++j)
            acc += inv.v[i * KP3 + j] * sc[j * 2 + c];
        // fold the 0.5 of r = d^2 * 0.5*log(d^2) into the RBF coefficients
        sT[x] = (i >= 3) ? 0.5f * acc : acc;
    }
    __syncthreads();

    float gx = ((float)x + 0.5f) * (1.0f / OW);

    // dx^2 to the 10 distinct control-point x positions — invariant across
    // the top/bottom cp rows and across both output rows this thread handles.
    float dx2[10];
    #pragma unroll
    for (int j = 0; j < 10; ++j) {
        float dx = gx - (0.05f + 0.1f * (float)j);
        dx2[j] = dx * dx;
    }

    int ybase = ytile * RPB;
    float gy0 = ((float)ybase + 0.5f) * (1.0f / OH);
    float gy1 = ((float)ybase + 1.5f) * (1.0f / OH);

    // ---- two independent RBF evaluations, interleaved for ILP ----
    float pxa = sT[0] + gx * sT[2] + gy0 * sT[4];
    float pya = sT[1] + gx * sT[3] + gy0 * sT[5];
    float pxb = sT[0] + gx * sT[2] + gy1 * sT[4];
    float pyb = sT[1] + gx * sT[3] + gy1 * sT[5];

    float da0 = gy0 - 0.05f, da1 = gy0 - 0.95f;
    float db0 = gy1 - 0.05f, db1 = gy1 - 0.95f;
    float dyyA0 = da0 * da0, dyyA1 = da1 * da1;
    float dyyB0 = db0 * db0, dyyB1 = db1 * db1;

    #pragma unroll
    for (int i = 0; i < KCP; ++i) {
        float dxx = dx2[i % 10];
        float d2a = dxx + ((i < 10) ? dyyA0 : dyyA1);
        float d2b = dxx + ((i < 10) ? dyyB0 : dyyB1);
        float ma = d2a * __logf(d2a);     // = 2*d^2*log(d); 0.5 folded in sT
        float mb = d2b * __logf(d2b);
        float c0 = sT[(3 + i) * 2 + 0], c1 = sT[(3 + i) * 2 + 1];
        pxa += ma * c0;  pya += ma * c1;
        pxb += mb * c0;  pyb += mb * c1;
    }

    // ---- addresses for both rows, then ALL loads, then all blend math ----
    float GxA = fminf(fmaxf((float)IW * pxa, 0.0f), (float)(IW - 2));
    float GyA = fminf(fmaxf((float)IH * pya, 0.0f), (float)(IH - 2));
    float GxB = fminf(fmaxf((float)IW * pxb, 0.0f), (float)(IW - 2));
    float GyB = fminf(fmaxf((float)IH * pyb, 0.0f), (float)(IH - 2));

    float fxA0 = floorf(GxA), fyA0 = floorf(GyA);
    float fxB0 = floorf(GxB), fyB0 = floorf(GyB);
    int xA = (int)fxA0, yA = (int)fyA0;
    int xB = (int)fxB0, yB = (int)fyB0;
    float fxa = GxA - fxA0, fya = GyA - fyA0;
    float fxb = GxB - fxB0, fyb = GyB - fyB0;

    const float* pA0 = X + (((size_t)b * IH + yA) * IW + xA) * CH;
    const float* pA1 = pA0 + (size_t)IW * CH;
    const float* pB0 = X + (((size_t)b * IH + yB) * IW + xB) * CH;
    const float* pB1 = pB0 + (size_t)IW * CH;

    // 24 contiguous bytes per row segment (pixels x0,x1 x 3ch), align 4.
    // memcpy → wide unaligned loads. Exactly in-bounds (x0<=510,y0<=126).
    // All four issued together: lanes' y differ (warped rows), so these are
    // scattered loads — keep 4 in flight per thread.
    float rA0[6], rA1[6], rB0[6], rB1[6];
    __builtin_memcpy(rA0, pA0, 24);
    __builtin_memcpy(rA1, pA1, 24);
    __builtin_memcpy(rB0, pB0, 24);
    __builtin_memcpy(rB1, pB1, 24);

    float wA00 = (1.0f - fxa) * (1.0f - fya);
    float wA10 = fxa * (1.0f - fya);
    float wA01 = (1.0f - fxa) * fya;
    float wA11 = fxa * fya;
    float wB00 = (1.0f - fxb) * (1.0f - fyb);
    float wB10 = fxb * (1.0f - fyb);
    float wB01 = (1.0f - fxb) * fyb;
    float wB11 = fxb * fyb;

    float oA0 = wA00 * rA0[0] + wA10 * rA0[3] + wA01 * rA1[0] + wA11 * rA1[3];
    float oA1 = wA00 * rA0[1] + wA10 * rA0[4] + wA01 * rA1[1] + wA11 * rA1[4];
    float oA2 = wA00 * rA0[2] + wA10 * rA0[5] + wA01 * rA1[2] + wA11 * rA1[5];
    float oB0 = wB00 * rB0[0] + wB10 * rB0[3] + wB01 * rB1[0] + wB11 * rB1[3];
    float oB1 = wB00 * rB0[1] + wB10 * rB0[4] + wB01 * rB1[1] + wB11 * rB1[4];
    float oB2 = wB00 * rB0[2] + wB10 * rB0[5] + wB01 * rB1[2] + wB11 * rB1[5];

    // out is write-once — nontemporal keeps it from evicting X in L2.
    float* oA = out + (((size_t)b * OH + ybase) * OW + x) * CH;
    float* oB = oA + (size_t)OW * CH;
    __builtin_nontemporal_store(oA0, oA + 0);
    __builtin_nontemporal_store(oA1, oA + 1);
    __builtin_nontemporal_store(oA2, oA + 2);
    __builtin_nontemporal_store(oB0, oB + 0);
    __builtin_nontemporal_store(oB1, oB + 1);
    __builtin_nontemporal_store(oB2, oB + 2);
}

// ---------------------------------------------------------------------------
// Host
// ---------------------------------------------------------------------------
extern "C" void kernel_launch(void* const* d_in, const int* in_sizes, int n_in,
                              void* d_out, int out_size, void* d_ws, size_t ws_size,
                              hipStream_t stream) {
    const float* X    = (const float*)d_in[0];
    const float* ctrl = (const float*)d_in[1];
    float* out = (float*)d_out;

    // ---- host-side: control points + inverse delta matrix (float64) ----
    double C[KCP][2];
    for (int j = 0; j < 10; ++j) {
        C[j][0]      = 0.05 + 0.1 * j;  C[j][1]      = 0.05;
        C[10 + j][0] = 0.05 + 0.1 * j;  C[10 + j][1] = 0.95;
    }

    double A[KP3][2 * KP3];
    for (int i = 0; i < KP3; ++i)
        for (int j = 0; j < 2 * KP3; ++j) A[i][j] = 0.0;

    for (int i = 0; i < KCP; ++i) {
        A[i][0] = 1.0; A[i][1] = C[i][0]; A[i][2] = C[i][1];
        for (int j = 0; j < KCP; ++j) {
            if (i == j) { A[i][3 + j] = 0.0; continue; }
            double dx = C[i][0] - C[j][0], dy = C[i][1] - C[j][1];
            double r2 = dx * dx + dy * dy;
            A[i][3 + j] = 0.5 * r2 * log(r2);   // r^2 * log(r)
        }
    }
    for (int j = 0; j < KCP; ++j) {
        A[KCP + 0][3 + j] = C[j][0];
        A[KCP + 1][3 + j] = C[j][1];
        A[KCP + 2][3 + j] = 1.0;
    }
    for (int i = 0; i < KP3; ++i) A[i][KP3 + i] = 1.0;   // augment identity

    // Gauss-Jordan with partial pivoting (float64, host)
    for (int k = 0; k < KP3; ++k) {
        int p = k; double best = fabs(A[k][k]);
        for (int i = k + 1; i < KP3; ++i)
            if (fabs(A[i][k]) > best) { best = fabs(A[i][k]); p = i; }
        if (p != k)
            for (int j = 0; j < 2 * KP3; ++j) { double t = A[k][j]; A[k][j] = A[p][j]; A[p][j] = t; }
        double pv = A[k][k];
        for (int j = 0; j < 2 * KP3; ++j) A[k][j] /= pv;
        for (int i = 0; i < KP3; ++i) {
            if (i == k) continue;
            double m = A[i][k];
            if (m == 0.0) continue;
            for (int j = 0; j < 2 * KP3; ++j) A[i][j] -= m * A[k][j];
        }
    }

    InvMat inv;
    for (int i = 0; i < KP3; ++i)
        for (int j = 0; j < KP3; ++j)
            inv.v[i * KP3 + j] = (float)A[i][KP3 + j];

    // ---- device: single fused kernel, RPB rows per block ----
    tps_fused_kernel<<<BATCH * YTILES, 256, 0, stream>>>(inv, ctrl, X, out);
}